// Round 5
// baseline (369.922 us; speedup 1.0000x reference)
//
#include <hip/hip_runtime.h>
#include <hip/hip_bf16.h>
#include <math.h>

constexpr int D  = 64;
constexpr int T  = 200;
constexpr int H0 = 80;
constexpr int H1 = 40;
constexpr int BLOCK = 256;
constexpr float NEG_INF_V = -4294967295.0f;

typedef short short8 __attribute__((ext_vector_type(8)));
typedef float f32x4 __attribute__((ext_vector_type(4)));
typedef int   int4v __attribute__((ext_vector_type(4)));

// RNE fp32->bf16 (hardware cvt), raw bits
__device__ inline unsigned short bf16h(float x) {
    __hip_bfloat16 t = __float2bfloat16(x);
    union { __hip_bfloat16 v; unsigned short u; } c; c.v = t; return c.u;
}
// RNE packed pair: low16 = bf16(a), high16 = bf16(b)
__device__ inline unsigned pk_bf16(float a, float b) {
    float2 f2; f2.x = a; f2.y = b;
    __hip_bfloat162 t = __float22bfloat162_rn(f2);
    union { __hip_bfloat162 v; unsigned u; } c; c.v = t; return c.u;
}
// split pair to (hi word, lo word)
__device__ inline void pk_split(float a, float b, unsigned& hi, unsigned& lo) {
    hi = pk_bf16(a, b);
    const float e0 = a - __uint_as_float(hi << 16);
    const float e1 = b - __uint_as_float(hi & 0xffff0000u);
    lo = pk_bf16(e0, e1);
}
__device__ inline short8 mk8(int w0, int w1, int w2, int w3) {
    union { int4v i; short8 s; } u;
    u.i = (int4v){w0, w1, w2, w3};
    return u.s;
}
#define BPERM(ad, v) __builtin_amdgcn_ds_bpermute((ad), (int)(v))
#define MFMA(A, B, C) __builtin_amdgcn_mfma_f32_16x16x32_bf16((A), (B), (C), 0, 0, 0)

// ============ Fully fused kernel, 2-tile-per-wave ILP ============
// One block per batch b, 4 waves. Each wave processes a PAIR of M-tiles per
// iteration (mtA = wv+8*ii, mtB = min(mtA+4,12); the clamped duplicates of
// tile 12 write identical values -> benign). Pairing gives every serial
// structure a partner to overlap with (two independent MFMA chains per nt,
// two pipelined bpermute transposes) and halves shared-operand loads
// (weff A-frags, W1 B-frags, bias/alpha are loaded once per pair).
// Phase 0: fold weff/W1 into split-bf16 MFMA frags in LDS (coalesced reads);
//   biasq[h] = b0[h] + sum_d q_d*(W0[d][h]+W0[128+d][h]). Mask + first pair
//   of k-tiles issued BEFORE the fold (HBM latency hides under it).
// Phase 1 per pair: L1 computes C1^T = weff(A) x K^T(B): lane holds
//   h0[h=ht*16+quad*4+reg][m=l16]; PReLU in-register; pack split-bf16 into
//   named uint2 scalars (NO arrays -> no rule-#20 scratch). Layer2 A-frags
//   (m=l16, k2=quad*8+j) via quad-level ds_bpermute transpose, hand-unrolled.
//   k2>=80 zero-padded. Head dot + shfl_xor reduce -> s_logits.
// Phase 2: softmax over T + out[b,d] = sum_t w_t v[b,t,d].
__global__ __launch_bounds__(BLOCK, 2) void attn_fused(
    const float* __restrict__ q, const float* __restrict__ k,
    const float* __restrict__ v, const float* __restrict__ W0,
    const float* __restrict__ b0, const float* __restrict__ a0,
    const float* __restrict__ W1, const float* __restrict__ b1,
    const float* __restrict__ a1, const float* __restrict__ Wo,
    const int* __restrict__ mask, float* __restrict__ out)
{
    __shared__ unsigned short s_wfHi[5120];       // 10 KB  weff A-frags hi
    __shared__ unsigned short s_wfLo[5120];       // 10 KB
    __shared__ unsigned short s_w1Hi[4608];       // 9 KB   W1 B-frags hi
    __shared__ unsigned short s_w1Lo[4608];       // 9 KB
    __shared__ float s_logits[208];
    __shared__ float s_biasq[H0];
    __shared__ float s_a0[H0];
    __shared__ float s_b1p[48], s_a1p[48], s_Wop[48];
    __shared__ float s_w[BLOCK];
    __shared__ float s_red[8];
    __shared__ float s_part[4][D];

    const int tid  = threadIdx.x;
    const int b    = blockIdx.x;
    const int wv   = tid >> 6;
    const int lane = tid & 63;
    const int l16  = lane & 15;
    const int quad = lane >> 4;
    const bool hiQ = (quad >= 2);
    const float* qb = q + (size_t)b * D;
    const float* kb_base = k + (size_t)b * T * D;

    // ---- early global issues: mask + first PAIR of k tiles ----
    const int mval = (tid < T) ? mask[(size_t)b * T + tid] : 0;
    float4 kA0, kA1, kA2, kA3, kB0, kB1, kB2, kB3;
    {
        int rA = wv * 16 + l16;        if (rA > T - 1) rA = T - 1;
        int rB = (wv + 4) * 16 + l16;  if (rB > T - 1) rB = T - 1;
        const float* pA = kb_base + (size_t)rA * D + quad * 8;
        const float* pB = kb_base + (size_t)rB * D + quad * 8;
        kA0 = *(const float4*)(pA);      kB0 = *(const float4*)(pB);
        kA1 = *(const float4*)(pA + 4);  kB1 = *(const float4*)(pB + 4);
        kA2 = *(const float4*)(pA + 32); kB2 = *(const float4*)(pB + 32);
        kA3 = *(const float4*)(pA + 36); kB3 = *(const float4*)(pB + 36);
    }

    // ---- Phase 0: fold weff into LDS A-frags (coalesced W0 reads) ----
    const float* Wk = W0 + 64 * H0;
    const float* Wd = W0 + 128 * H0;
    const float* Wp = W0 + 192 * H0;
    #pragma unroll 4
    for (int it = 0; it < 20; ++it) {
        const int e  = it * 256 + tid;            // e in [0, 5120)
        const int kk = e / 80, h = e - kk * 80;
        const float w = Wk[e] - Wd[e] + qb[kk] * Wp[e];
        const unsigned short hb = bf16h(w);
        const unsigned short lb = bf16h(w - __uint_as_float((unsigned)hb << 16));
        // A-frag: lane = ((kk>>3)&3)*16 + (h&15), j = kk&7
        const int off = (((kk >> 5) * 5 + (h >> 4)) << 9)
                      + (((((kk >> 3) & 3) << 4) + (h & 15)) << 3) + (kk & 7);
        s_wfHi[off] = hb; s_wfLo[off] = lb;
    }
    // W1 B-frags, padded 96x48 with zeros
    #pragma unroll 4
    for (int it = 0; it < 18; ++it) {
        const int e  = it * 256 + tid;            // e in [0, 4608)
        const int k2 = e / 48, n = e - k2 * 48;
        const float w = (k2 < H0 && n < H1) ? W1[k2 * H1 + n] : 0.0f;
        const unsigned short hb = bf16h(w);
        const unsigned short lb = bf16h(w - __uint_as_float((unsigned)hb << 16));
        const int off = (((k2 >> 5) * 3 + (n >> 4)) << 9)
                      + (((((k2 >> 3) & 3) << 4) + (n & 15)) << 3) + (k2 & 7);
        s_w1Hi[off] = hb; s_w1Lo[off] = lb;
    }
    // biasq + per-feature consts
    if (tid < H0) {
        float acc = b0[tid];
        #pragma unroll 8
        for (int d = 0; d < D; ++d)
            acc = fmaf(qb[d], W0[d * H0 + tid] + W0[(128 + d) * H0 + tid], acc);
        s_biasq[tid] = acc;
        s_a0[tid]    = a0[tid];
    }
    if (tid < 48) {
        s_b1p[tid] = (tid < H1) ? b1[tid] : 0.0f;
        s_a1p[tid] = (tid < H1) ? a1[tid] : 0.0f;
        s_Wop[tid] = (tid < H1) ? Wo[tid] : 0.0f;
    }
    __syncthreads();

    // bpermute source byte-addrs: lane (2*(quad&1) + {0,1})*16 + l16
    const int addr0 = (((quad & 1) << 5) + l16) << 2;
    const int addr1 = addr0 + 64;

// K^T B-frag build (lane: n=l16 row of K, k=quad*8+j), split bf16
#define KBUILD(C0, C1, C2, C3, BH0, BL0, BH1, BL1) { \
    unsigned h0_, l0_, h1_, l1_, h2_, l2_, h3_, l3_; \
    pk_split(C0.x, C0.y, h0_, l0_); pk_split(C0.z, C0.w, h1_, l1_); \
    pk_split(C1.x, C1.y, h2_, l2_); pk_split(C1.z, C1.w, h3_, l3_); \
    BH0 = mk8((int)h0_, (int)h1_, (int)h2_, (int)h3_); \
    BL0 = mk8((int)l0_, (int)l1_, (int)l2_, (int)l3_); \
    pk_split(C2.x, C2.y, h0_, l0_); pk_split(C2.z, C2.w, h1_, l1_); \
    pk_split(C3.x, C3.y, h2_, l2_); pk_split(C3.z, C3.w, h3_, l3_); \
    BH1 = mk8((int)h0_, (int)h1_, (int)h2_, (int)h3_); \
    BL1 = mk8((int)l0_, (int)l1_, (int)l2_, (int)l3_); }

// Layer-1 h-tile HT for BOTH tiles: shared A-frag loads, 12 MFMAs (2 chains),
// shared bias/alpha, dual PReLU+pack into named uint2s
#define L1_NT(HT, HWA, LWA, HWB, LWB) { \
    const short8 Ah0_ = *(const short8*)&s_wfHi[(0 * 5 + HT) * 512 + lane * 8]; \
    const short8 Al0_ = *(const short8*)&s_wfLo[(0 * 5 + HT) * 512 + lane * 8]; \
    const short8 Ah1_ = *(const short8*)&s_wfHi[(1 * 5 + HT) * 512 + lane * 8]; \
    const short8 Al1_ = *(const short8*)&s_wfLo[(1 * 5 + HT) * 512 + lane * 8]; \
    f32x4 aA_ = {0.0f, 0.0f, 0.0f, 0.0f}, aB_ = {0.0f, 0.0f, 0.0f, 0.0f}; \
    aA_ = MFMA(Ah0_, kAhi0, aA_);  aB_ = MFMA(Ah0_, kBhi0, aB_); \
    aA_ = MFMA(Ah0_, kAlo0, aA_);  aB_ = MFMA(Ah0_, kBlo0, aB_); \
    aA_ = MFMA(Al0_, kAhi0, aA_);  aB_ = MFMA(Al0_, kBhi0, aB_); \
    aA_ = MFMA(Ah1_, kAhi1, aA_);  aB_ = MFMA(Ah1_, kBhi1, aB_); \
    aA_ = MFMA(Ah1_, kAlo1, aA_);  aB_ = MFMA(Ah1_, kBlo1, aB_); \
    aA_ = MFMA(Al1_, kAhi1, aA_);  aB_ = MFMA(Al1_, kBhi1, aB_); \
    const int hb_ = HT * 16 + quad * 4; \
    const float c0_ = s_biasq[hb_ + 0], c1_ = s_biasq[hb_ + 1]; \
    const float c2_ = s_biasq[hb_ + 2], c3_ = s_biasq[hb_ + 3]; \
    const float p0_ = s_a0[hb_ + 0], p1_ = s_a0[hb_ + 1]; \
    const float p2_ = s_a0[hb_ + 2], p3_ = s_a0[hb_ + 3]; \
    { const float x0_ = aA_[0] + c0_, x1_ = aA_[1] + c1_; \
      const float x2_ = aA_[2] + c2_, x3_ = aA_[3] + c3_; \
      const float f0_ = (x0_ >= 0.0f) ? x0_ : p0_ * x0_; \
      const float f1_ = (x1_ >= 0.0f) ? x1_ : p1_ * x1_; \
      const float f2_ = (x2_ >= 0.0f) ? x2_ : p2_ * x2_; \
      const float f3_ = (x3_ >= 0.0f) ? x3_ : p3_ * x3_; \
      pk_split(f0_, f1_, HWA.x, LWA.x); pk_split(f2_, f3_, HWA.y, LWA.y); } \
    { const float x0_ = aB_[0] + c0_, x1_ = aB_[1] + c1_; \
      const float x2_ = aB_[2] + c2_, x3_ = aB_[3] + c3_; \
      const float f0_ = (x0_ >= 0.0f) ? x0_ : p0_ * x0_; \
      const float f1_ = (x1_ >= 0.0f) ? x1_ : p1_ * x1_; \
      const float f2_ = (x2_ >= 0.0f) ? x2_ : p2_ * x2_; \
      const float f3_ = (x3_ >= 0.0f) ? x3_ : p3_ * x3_; \
      pk_split(f0_, f1_, HWB.x, LWB.x); pk_split(f2_, f3_, HWB.y, LWB.y); } }

// Transpose k2-step from (HA=even-ht, HB=odd-ht) words to A-frag AHI/ALO
#define TRN(HA, HB, LA, LB, AHI, ALO) { \
    int h0_ = BPERM(addr0, HA.x), h1_ = BPERM(addr0, HA.y); \
    int h2_ = BPERM(addr1, HA.x), h3_ = BPERM(addr1, HA.y); \
    int g0_ = BPERM(addr0, HB.x), g1_ = BPERM(addr0, HB.y); \
    int g2_ = BPERM(addr1, HB.x), g3_ = BPERM(addr1, HB.y); \
    AHI = mk8(hiQ ? g0_ : h0_, hiQ ? g1_ : h1_, hiQ ? g2_ : h2_, hiQ ? g3_ : h3_); \
    int l0_ = BPERM(addr0, LA.x), l1_ = BPERM(addr0, LA.y); \
    int l2_ = BPERM(addr1, LA.x), l3_ = BPERM(addr1, LA.y); \
    int m0_ = BPERM(addr0, LB.x), m1_ = BPERM(addr0, LB.y); \
    int m2_ = BPERM(addr1, LB.x), m3_ = BPERM(addr1, LB.y); \
    ALO = mk8(hiQ ? m0_ : l0_, hiQ ? m1_ : l1_, hiQ ? m2_ : l2_, hiQ ? m3_ : l3_); }

// Last k2-step: only ht=4 exists (k2 in [64,80)); quad>=2 -> zeros
#define TRN2(HA, LA, AHI, ALO) { \
    int h0_ = BPERM(addr0, HA.x), h1_ = BPERM(addr0, HA.y); \
    int h2_ = BPERM(addr1, HA.x), h3_ = BPERM(addr1, HA.y); \
    AHI = mk8(hiQ ? 0 : h0_, hiQ ? 0 : h1_, hiQ ? 0 : h2_, hiQ ? 0 : h3_); \
    int l0_ = BPERM(addr0, LA.x), l1_ = BPERM(addr0, LA.y); \
    int l2_ = BPERM(addr1, LA.x), l3_ = BPERM(addr1, LA.y); \
    ALO = mk8(hiQ ? 0 : l0_, hiQ ? 0 : l1_, hiQ ? 0 : l2_, hiQ ? 0 : l3_); }

// Layer-2 n-tile NT2 for BOTH tiles: shared W1 B-frag loads, 18 MFMAs,
// shared epilogue consts, dual head-dot
#define L2_NT(NT2) { \
    f32x4 aA_ = {0.0f, 0.0f, 0.0f, 0.0f}, aB_ = {0.0f, 0.0f, 0.0f, 0.0f}; \
    { const short8 bh_ = *(const short8*)&s_w1Hi[(0 * 3 + NT2) * 512 + lane * 8]; \
      const short8 bl_ = *(const short8*)&s_w1Lo[(0 * 3 + NT2) * 512 + lane * 8]; \
      aA_ = MFMA(a2Ahi0, bh_, aA_);  aB_ = MFMA(a2Bhi0, bh_, aB_); \
      aA_ = MFMA(a2Ahi0, bl_, aA_);  aB_ = MFMA(a2Bhi0, bl_, aB_); \
      aA_ = MFMA(a2Alo0, bh_, aA_);  aB_ = MFMA(a2Blo0, bh_, aB_); } \
    { const short8 bh_ = *(const short8*)&s_w1Hi[(1 * 3 + NT2) * 512 + lane * 8]; \
      const short8 bl_ = *(const short8*)&s_w1Lo[(1 * 3 + NT2) * 512 + lane * 8]; \
      aA_ = MFMA(a2Ahi1, bh_, aA_);  aB_ = MFMA(a2Bhi1, bh_, aB_); \
      aA_ = MFMA(a2Ahi1, bl_, aA_);  aB_ = MFMA(a2Bhi1, bl_, aB_); \
      aA_ = MFMA(a2Alo1, bh_, aA_);  aB_ = MFMA(a2Blo1, bh_, aB_); } \
    { const short8 bh_ = *(const short8*)&s_w1Hi[(2 * 3 + NT2) * 512 + lane * 8]; \
      const short8 bl_ = *(const short8*)&s_w1Lo[(2 * 3 + NT2) * 512 + lane * 8]; \
      aA_ = MFMA(a2Ahi2, bh_, aA_);  aB_ = MFMA(a2Bhi2, bh_, aB_); \
      aA_ = MFMA(a2Ahi2, bl_, aA_);  aB_ = MFMA(a2Bhi2, bl_, aB_); \
      aA_ = MFMA(a2Alo2, bh_, aA_);  aB_ = MFMA(a2Blo2, bh_, aB_); } \
    const int g_ = NT2 * 16 + l16; \
    const float bg_ = s_b1p[g_], ag_ = s_a1p[g_], wg_ = s_Wop[g_]; \
    { const float x_ = aA_[0] + bg_; partA0 = fmaf((x_ >= 0.0f) ? x_ : ag_ * x_, wg_, partA0); } \
    { const float x_ = aA_[1] + bg_; partA1 = fmaf((x_ >= 0.0f) ? x_ : ag_ * x_, wg_, partA1); } \
    { const float x_ = aA_[2] + bg_; partA2 = fmaf((x_ >= 0.0f) ? x_ : ag_ * x_, wg_, partA2); } \
    { const float x_ = aA_[3] + bg_; partA3 = fmaf((x_ >= 0.0f) ? x_ : ag_ * x_, wg_, partA3); } \
    { const float x_ = aB_[0] + bg_; partB0 = fmaf((x_ >= 0.0f) ? x_ : ag_ * x_, wg_, partB0); } \
    { const float x_ = aB_[1] + bg_; partB1 = fmaf((x_ >= 0.0f) ? x_ : ag_ * x_, wg_, partB1); } \
    { const float x_ = aB_[2] + bg_; partB2 = fmaf((x_ >= 0.0f) ? x_ : ag_ * x_, wg_, partB2); } \
    { const float x_ = aB_[3] + bg_; partB3 = fmaf((x_ >= 0.0f) ? x_ : ag_ * x_, wg_, partB3); } }

    // ---- Phase 1: two pair-iterations per wave ----
    for (int ii = 0; ii < 2; ++ii) {
        const int mtA = wv + ii * 8;
        const int mtB = (mtA + 4 > 12) ? 12 : (mtA + 4);
        // prefetch next pair's k rows (ii==0 only)
        float4 nA0, nA1, nA2, nA3, nB0, nB1, nB2, nB3;
        if (ii == 0) {
            int rA = (wv + 8) * 16 + l16;                 if (rA > T - 1) rA = T - 1;
            int tB = (wv + 12 > 12) ? 12 : (wv + 12);
            int rB = tB * 16 + l16;                       if (rB > T - 1) rB = T - 1;
            const float* pA = kb_base + (size_t)rA * D + quad * 8;
            const float* pB = kb_base + (size_t)rB * D + quad * 8;
            nA0 = *(const float4*)(pA);      nB0 = *(const float4*)(pB);
            nA1 = *(const float4*)(pA + 4);  nB1 = *(const float4*)(pB + 4);
            nA2 = *(const float4*)(pA + 32); nB2 = *(const float4*)(pB + 32);
            nA3 = *(const float4*)(pA + 36); nB3 = *(const float4*)(pB + 36);
        }
        // K^T B-frags for both tiles
        short8 kAhi0, kAlo0, kAhi1, kAlo1, kBhi0, kBlo0, kBhi1, kBlo1;
        KBUILD(kA0, kA1, kA2, kA3, kAhi0, kAlo0, kAhi1, kAlo1)
        KBUILD(kB0, kB1, kB2, kB3, kBhi0, kBlo0, kBhi1, kBlo1)
        // ---- Layer 1: 5 h-tiles, both tiles interleaved ----
        uint2 hwA0, hwA1, hwA2, hwA3, hwA4, lwA0, lwA1, lwA2, lwA3, lwA4;
        uint2 hwB0, hwB1, hwB2, hwB3, hwB4, lwB0, lwB1, lwB2, lwB3, lwB4;
        L1_NT(0, hwA0, lwA0, hwB0, lwB0)
        L1_NT(1, hwA1, lwA1, hwB1, lwB1)
        L1_NT(2, hwA2, lwA2, hwB2, lwB2)
        L1_NT(3, hwA3, lwA3, hwB3, lwB3)
        L1_NT(4, hwA4, lwA4, hwB4, lwB4)
        // ---- Layer 2 A-frags via bpermute transpose, both tiles ----
        short8 a2Ahi0, a2Alo0, a2Ahi1, a2Alo1, a2Ahi2, a2Alo2;
        short8 a2Bhi0, a2Blo0, a2Bhi1, a2Blo1, a2Bhi2, a2Blo2;
        TRN(hwA0, hwA1, lwA0, lwA1, a2Ahi0, a2Alo0)
        TRN(hwA2, hwA3, lwA2, lwA3, a2Ahi1, a2Alo1)
        TRN2(hwA4, lwA4, a2Ahi2, a2Alo2)
        TRN(hwB0, hwB1, lwB0, lwB1, a2Bhi0, a2Blo0)
        TRN(hwB2, hwB3, lwB2, lwB3, a2Bhi1, a2Blo1)
        TRN2(hwB4, lwB4, a2Bhi2, a2Blo2)
        // ---- Layer 2 + head, both tiles ----
        float partA0 = 0.0f, partA1 = 0.0f, partA2 = 0.0f, partA3 = 0.0f;
        float partB0 = 0.0f, partB1 = 0.0f, partB2 = 0.0f, partB3 = 0.0f;
        L2_NT(0)
        L2_NT(1)
        L2_NT(2)
        // reduce over the 16 g-cols (lane bits 0..3)
        #pragma unroll
        for (int off = 1; off < 16; off <<= 1) {
            partA0 += __shfl_xor(partA0, off);
            partA1 += __shfl_xor(partA1, off);
            partA2 += __shfl_xor(partA2, off);
            partA3 += __shfl_xor(partA3, off);
            partB0 += __shfl_xor(partB0, off);
            partB1 += __shfl_xor(partB1, off);
            partB2 += __shfl_xor(partB2, off);
            partB3 += __shfl_xor(partB3, off);
        }
        if (l16 == 0) {
            float4 pA = {partA0, partA1, partA2, partA3};
            float4 pB = {partB0, partB1, partB2, partB3};
            *(float4*)&s_logits[mtA * 16 + quad * 4] = pA;
            // mtB duplicates (waves 1-3, ii=1) write identical values - benign
            *(float4*)&s_logits[mtB * 16 + quad * 4] = pB;
        }
        if (ii == 0) {
            kA0 = nA0; kA1 = nA1; kA2 = nA2; kA3 = nA3;
            kB0 = nB0; kB1 = nB1; kB2 = nB2; kB3 = nB3;
        }
    }
    __syncthreads();

    // ---- Phase 2: mask + softmax over T (pads -> -inf => exp 0) ----
    float logit = -INFINITY;
    if (tid < T)
        logit = (mval == 0) ? NEG_INF_V : s_logits[tid];

    float m = logit;
    #pragma unroll
    for (int off = 32; off > 0; off >>= 1) m = fmaxf(m, __shfl_xor(m, off));
    if (lane == 0) s_red[wv] = m;
    __syncthreads();
    m = fmaxf(fmaxf(s_red[0], s_red[1]), fmaxf(s_red[2], s_red[3]));
    const float e = expf(logit - m);
    s_w[tid] = e;
    float ssum = e;
    #pragma unroll
    for (int off = 32; off > 0; off >>= 1) ssum += __shfl_xor(ssum, off);
    if (lane == 0) s_red[4 + wv] = ssum;
    __syncthreads();
    const float inv = 1.0f / (s_red[4] + s_red[5] + s_red[6] + s_red[7]);

    // ---- out[b,d] = sum_t w_t * v[b,t,d] (coalesced in d) ----
    const int d = tid & (D - 1);
    const int c = tid >> 6;
    constexpr int TC = T / 4;          // 50
    float acc2 = 0.0f;
    const float* vp = v + ((size_t)b * T + c * TC) * D + d;
    #pragma unroll 10
    for (int t = 0; t < TC; ++t)
        acc2 = fmaf(s_w[c * TC + t], vp[t * D], acc2);
    s_part[c][d] = acc2;
    __syncthreads();
    if (tid < D) {
        out[(size_t)b * D + tid] =
            (s_part[0][tid] + s_part[1][tid] + s_part[2][tid] + s_part[3][tid]) * inv;
    }
}

extern "C" void kernel_launch(void* const* d_in, const int* in_sizes, int n_in,
                              void* d_out, int out_size, void* d_ws, size_t ws_size,
                              hipStream_t stream) {
    const float* q  = (const float*)d_in[0];
    const float* k  = (const float*)d_in[1];
    const float* v  = (const float*)d_in[2];
    const float* W0 = (const float*)d_in[3];
    const float* b0 = (const float*)d_in[4];
    const float* a0 = (const float*)d_in[5];
    const float* W1 = (const float*)d_in[6];
    const float* b1 = (const float*)d_in[7];
    const float* a1 = (const float*)d_in[8];
    const float* Wo = (const float*)d_in[9];
    const int*  mask = (const int*)d_in[11];
    float* out = (float*)d_out;

    const int B = in_sizes[0] / D;            // 2048

    attn_fused<<<dim3(B), dim3(BLOCK), 0, stream>>>(
        q, k, v, W0, b0, a0, W1, b1, a1, Wo, mask, out);
}

// Round 6
// 303.586 us; speedup vs baseline: 1.2185x; 1.2185x over previous
//
#include <hip/hip_runtime.h>
#include <hip/hip_bf16.h>
#include <math.h>

constexpr int D  = 64;
constexpr int T  = 200;
constexpr int H0 = 80;
constexpr int H1 = 40;
constexpr int BLOCK = 256;
constexpr float NEG_INF_V = -4294967295.0f;

typedef short short8 __attribute__((ext_vector_type(8)));
typedef float f32x4 __attribute__((ext_vector_type(4)));
typedef int   int4v __attribute__((ext_vector_type(4)));

// RNE fp32->bf16 (hardware cvt), raw bits
__device__ inline unsigned short bf16h(float x) {
    __hip_bfloat16 t = __float2bfloat16(x);
    union { __hip_bfloat16 v; unsigned short u; } c; c.v = t; return c.u;
}
// RNE packed pair: low16 = bf16(a), high16 = bf16(b)
__device__ inline unsigned pk_bf16(float a, float b) {
    float2 f2; f2.x = a; f2.y = b;
    __hip_bfloat162 t = __float22bfloat162_rn(f2);
    union { __hip_bfloat162 v; unsigned u; } c; c.v = t; return c.u;
}
// split pair to (hi word, lo word)
__device__ inline void pk_split(float a, float b, unsigned& hi, unsigned& lo) {
    hi = pk_bf16(a, b);
    const float e0 = a - __uint_as_float(hi << 16);
    const float e1 = b - __uint_as_float(hi & 0xffff0000u);
    lo = pk_bf16(e0, e1);
}
__device__ inline short8 mk8(int w0, int w1, int w2, int w3) {
    union { int4v i; short8 s; } u;
    u.i = (int4v){w0, w1, w2, w3};
    return u.s;
}
#define BPERM(ad, v) __builtin_amdgcn_ds_bpermute((ad), (int)(v))
#define MFMA(A, B, C) __builtin_amdgcn_mfma_f32_16x16x32_bf16((A), (B), (C), 0, 0, 0)

// ============ Pre-kernel: fold W1 into split-bf16 B-frags in ws ============
// Batch-independent (12.8 KB -> L2-resident for the main kernel).
// B-frag layout (16x16x32): frag (k2s,nt2), lane holds B[k2=k2s*32+quad*8+j]
// [n=nt2*16+l16]; zero-padded 96x48.
__global__ __launch_bounds__(256) void fold_w1(
    const float* __restrict__ W1, short* __restrict__ w1fHi,
    short* __restrict__ w1fLo)
{
    const int tid = threadIdx.x;
    for (int e = tid; e < 4608; e += 256) {
        const int k2 = e / 48, n = e - k2 * 48;
        const float w = (k2 < H0 && n < H1) ? W1[k2 * H1 + n] : 0.0f;
        const unsigned short hb = bf16h(w);
        const unsigned short lb = bf16h(w - __uint_as_float((unsigned)hb << 16));
        const int off = (((k2 >> 5) * 3 + (n >> 4)) << 9)
                      + (((((k2 >> 3) & 3) << 4) + (n & 15)) << 3) + (k2 & 7);
        w1fHi[off] = hb; w1fLo[off] = lb;
    }
}

// ============ Fully fused main kernel ============
// One block per batch b, 4 waves, target 4 blocks/CU (LDS ~24.6 KB, VGPR<=128).
// Phase 0: fold weff[kk][h] = W0[64+kk][h]-W0[128+kk][h]+q_kk*W0[192+kk][h]
//   into split-bf16 MFMA A-frags in LDS (m=h, k=kk); biasq[h] = b0[h] +
//   sum_d q_d*(W0[d][h]+W0[128+d][h]). Mask + first k-tile issued BEFORE the
//   fold (HBM latency hides under it). W1 B-frags come from ws via coalesced,
//   loop-invariant 16B global loads (L2-resident; no LDS).
// Phase 1: wave w owns M-tiles {w, w+4, ...} of 13 (M=200 pad 208).
//   Layer1 computes C1^T = weff(A) x K^T(B): lane holds
//   h0[h=ht*16+quad*4+reg][m=l16]; PReLU in-register; pack to split-bf16
//   named uint2 scalars (NO arrays -> no rule-#20 scratch). kc0..3 are
//   reloaded IN PLACE for tile mt+4 right after KBUILD consumes them
//   (prefetch with zero extra live registers -> no R5-style pressure spill).
//   Layer2 A-frags (m=l16, k2=quad*8+j) via quad-level ds_bpermute transpose,
//   hand-unrolled named scalars; k2>=80 zero. Head dot + shfl_xor -> s_logits.
// Phase 2: softmax over T + out[b,d] = sum_t w_t v[b,t,d].
__global__ __launch_bounds__(BLOCK, 2) void attn_fused(
    const float* __restrict__ q, const float* __restrict__ k,
    const float* __restrict__ v, const float* __restrict__ W0,
    const float* __restrict__ b0, const float* __restrict__ a0,
    const short* __restrict__ w1fHi, const short* __restrict__ w1fLo,
    const float* __restrict__ b1, const float* __restrict__ a1,
    const float* __restrict__ Wo, const int* __restrict__ mask,
    float* __restrict__ out)
{
    __shared__ unsigned short s_wfHi[5120];       // 10 KB  weff A-frags hi
    __shared__ unsigned short s_wfLo[5120];       // 10 KB
    __shared__ float s_logits[208];
    __shared__ float s_biasq[H0];
    __shared__ float s_a0[H0];
    __shared__ float s_b1p[48], s_a1p[48], s_Wop[48];
    __shared__ float s_w[BLOCK];
    __shared__ float s_red[8];
    __shared__ float s_part[4][D];

    const int tid  = threadIdx.x;
    const int b    = blockIdx.x;
    const int wv   = tid >> 6;
    const int lane = tid & 63;
    const int l16  = lane & 15;
    const int quad = lane >> 4;
    const bool hiQ = (quad >= 2);
    const float* qb = q + (size_t)b * D;
    const float* kb_base = k + (size_t)b * T * D;

    // ---- early global issues: mask + first k tile (latency hides under fold)
    const int mval = (tid < T) ? mask[(size_t)b * T + tid] : 0;
    float4 kc0, kc1, kc2, kc3;
    {
        int row = wv * 16 + l16; if (row > T - 1) row = T - 1;
        const float* kr = kb_base + (size_t)row * D + quad * 8;
        kc0 = *(const float4*)(kr);
        kc1 = *(const float4*)(kr + 4);
        kc2 = *(const float4*)(kr + 32);
        kc3 = *(const float4*)(kr + 36);
    }

    // ---- Phase 0: fold weff into LDS A-frags (coalesced W0 reads) ----
    const float* Wk = W0 + 64 * H0;
    const float* Wd = W0 + 128 * H0;
    const float* Wp = W0 + 192 * H0;
    #pragma unroll 4
    for (int it = 0; it < 20; ++it) {
        const int e  = it * 256 + tid;            // e in [0, 5120)
        const int kk = e / 80, h = e - kk * 80;
        const float w = Wk[e] - Wd[e] + qb[kk] * Wp[e];
        const unsigned short hb = bf16h(w);
        const unsigned short lb = bf16h(w - __uint_as_float((unsigned)hb << 16));
        // A-frag: lane = ((kk>>3)&3)*16 + (h&15), j = kk&7
        const int off = (((kk >> 5) * 5 + (h >> 4)) << 9)
                      + (((((kk >> 3) & 3) << 4) + (h & 15)) << 3) + (kk & 7);
        s_wfHi[off] = hb; s_wfLo[off] = lb;
    }
    // biasq + per-feature consts
    if (tid < H0) {
        float acc = b0[tid];
        #pragma unroll 8
        for (int d = 0; d < D; ++d)
            acc = fmaf(qb[d], W0[d * H0 + tid] + W0[(128 + d) * H0 + tid], acc);
        s_biasq[tid] = acc;
        s_a0[tid]    = a0[tid];
    }
    if (tid < 48) {
        s_b1p[tid] = (tid < H1) ? b1[tid] : 0.0f;
        s_a1p[tid] = (tid < H1) ? a1[tid] : 0.0f;
        s_Wop[tid] = (tid < H1) ? Wo[tid] : 0.0f;
    }
    __syncthreads();

    // bpermute source byte-addrs: lane (2*(quad&1) + {0,1})*16 + l16
    const int addr0 = (((quad & 1) << 5) + l16) << 2;
    const int addr1 = addr0 + 64;

// Layer-1 h-tile HT: 6 MFMAs -> PReLU -> pack into named uint2 HW/LW
#define L1_HT(HT, HW, LW) { \
    f32x4 acc_ = {0.0f, 0.0f, 0.0f, 0.0f}; \
    { short8 Ah_ = *(const short8*)&s_wfHi[(0 * 5 + HT) * 512 + lane * 8]; \
      short8 Al_ = *(const short8*)&s_wfLo[(0 * 5 + HT) * 512 + lane * 8]; \
      acc_ = MFMA(Ah_, kbhi0, acc_); \
      acc_ = MFMA(Ah_, kblo0, acc_); \
      acc_ = MFMA(Al_, kbhi0, acc_); } \
    { short8 Ah_ = *(const short8*)&s_wfHi[(1 * 5 + HT) * 512 + lane * 8]; \
      short8 Al_ = *(const short8*)&s_wfLo[(1 * 5 + HT) * 512 + lane * 8]; \
      acc_ = MFMA(Ah_, kbhi1, acc_); \
      acc_ = MFMA(Ah_, kblo1, acc_); \
      acc_ = MFMA(Al_, kbhi1, acc_); } \
    const int hb_ = HT * 16 + quad * 4; \
    const float x0_ = acc_[0] + s_biasq[hb_ + 0]; \
    const float x1_ = acc_[1] + s_biasq[hb_ + 1]; \
    const float x2_ = acc_[2] + s_biasq[hb_ + 2]; \
    const float x3_ = acc_[3] + s_biasq[hb_ + 3]; \
    const float f0_ = (x0_ >= 0.0f) ? x0_ : s_a0[hb_ + 0] * x0_; \
    const float f1_ = (x1_ >= 0.0f) ? x1_ : s_a0[hb_ + 1] * x1_; \
    const float f2_ = (x2_ >= 0.0f) ? x2_ : s_a0[hb_ + 2] * x2_; \
    const float f3_ = (x3_ >= 0.0f) ? x3_ : s_a0[hb_ + 3] * x3_; \
    pk_split(f0_, f1_, HW.x, LW.x); \
    pk_split(f2_, f3_, HW.y, LW.y); }

// Transpose k2-step from (HA=even-ht, HB=odd-ht) words to A-frag AHI/ALO
#define TRN(HA, HB, LA, LB, AHI, ALO) { \
    int h0_ = BPERM(addr0, HA.x), h1_ = BPERM(addr0, HA.y); \
    int h2_ = BPERM(addr1, HA.x), h3_ = BPERM(addr1, HA.y); \
    int g0_ = BPERM(addr0, HB.x), g1_ = BPERM(addr0, HB.y); \
    int g2_ = BPERM(addr1, HB.x), g3_ = BPERM(addr1, HB.y); \
    AHI = mk8(hiQ ? g0_ : h0_, hiQ ? g1_ : h1_, hiQ ? g2_ : h2_, hiQ ? g3_ : h3_); \
    int l0_ = BPERM(addr0, LA.x), l1_ = BPERM(addr0, LA.y); \
    int l2_ = BPERM(addr1, LA.x), l3_ = BPERM(addr1, LA.y); \
    int m0_ = BPERM(addr0, LB.x), m1_ = BPERM(addr0, LB.y); \
    int m2_ = BPERM(addr1, LB.x), m3_ = BPERM(addr1, LB.y); \
    ALO = mk8(hiQ ? m0_ : l0_, hiQ ? m1_ : l1_, hiQ ? m2_ : l2_, hiQ ? m3_ : l3_); }

// Last k2-step: only ht=4 exists (k2 in [64,80)); quad>=2 -> zeros
#define TRN2(HA, LA, AHI, ALO) { \
    int h0_ = BPERM(addr0, HA.x), h1_ = BPERM(addr0, HA.y); \
    int h2_ = BPERM(addr1, HA.x), h3_ = BPERM(addr1, HA.y); \
    AHI = mk8(hiQ ? 0 : h0_, hiQ ? 0 : h1_, hiQ ? 0 : h2_, hiQ ? 0 : h3_); \
    int l0_ = BPERM(addr0, LA.x), l1_ = BPERM(addr0, LA.y); \
    int l2_ = BPERM(addr1, LA.x), l3_ = BPERM(addr1, LA.y); \
    ALO = mk8(hiQ ? 0 : l0_, hiQ ? 0 : l1_, hiQ ? 0 : l2_, hiQ ? 0 : l3_); }

// Layer-2 n-tile NT2: 9 MFMAs (B-frags from global ws, L2-resident,
// loop-invariant addresses) + PReLU + head dot into part[]
#define L2_NT(NT2) { \
    f32x4 acc_ = {0.0f, 0.0f, 0.0f, 0.0f}; \
    { short8 bh_ = *(const short8*)&w1fHi[(0 * 3 + NT2) * 512 + lane * 8]; \
      short8 bl_ = *(const short8*)&w1fLo[(0 * 3 + NT2) * 512 + lane * 8]; \
      acc_ = MFMA(a2hi0, bh_, acc_); \
      acc_ = MFMA(a2hi0, bl_, acc_); \
      acc_ = MFMA(a2lo0, bh_, acc_); } \
    { short8 bh_ = *(const short8*)&w1fHi[(1 * 3 + NT2) * 512 + lane * 8]; \
      short8 bl_ = *(const short8*)&w1fLo[(1 * 3 + NT2) * 512 + lane * 8]; \
      acc_ = MFMA(a2hi1, bh_, acc_); \
      acc_ = MFMA(a2hi1, bl_, acc_); \
      acc_ = MFMA(a2lo1, bh_, acc_); } \
    { short8 bh_ = *(const short8*)&w1fHi[(2 * 3 + NT2) * 512 + lane * 8]; \
      short8 bl_ = *(const short8*)&w1fLo[(2 * 3 + NT2) * 512 + lane * 8]; \
      acc_ = MFMA(a2hi2, bh_, acc_); \
      acc_ = MFMA(a2hi2, bl_, acc_); \
      acc_ = MFMA(a2lo2, bh_, acc_); } \
    const int g_ = NT2 * 16 + l16; \
    const float bg_ = s_b1p[g_], ag_ = s_a1p[g_], wg_ = s_Wop[g_]; \
    { const float x_ = acc_[0] + bg_; part0 = fmaf((x_ >= 0.0f) ? x_ : ag_ * x_, wg_, part0); } \
    { const float x_ = acc_[1] + bg_; part1 = fmaf((x_ >= 0.0f) ? x_ : ag_ * x_, wg_, part1); } \
    { const float x_ = acc_[2] + bg_; part2 = fmaf((x_ >= 0.0f) ? x_ : ag_ * x_, wg_, part2); } \
    { const float x_ = acc_[3] + bg_; part3 = fmaf((x_ >= 0.0f) ? x_ : ag_ * x_, wg_, part3); } }

    // ---- Phase 1: per-wave M-tiles; kc reloaded in place (free prefetch) ----
    for (int mt = wv; mt < 13; mt += 4) {
        // K^T B-fragments (lane: n=l16 row of K, k=quad*8+j), split bf16
        short8 kbhi0, kblo0, kbhi1, kblo1;
        {
            unsigned h0_, l0_, h1_, l1_, h2_, l2_, h3_, l3_;
            pk_split(kc0.x, kc0.y, h0_, l0_);
            pk_split(kc0.z, kc0.w, h1_, l1_);
            pk_split(kc1.x, kc1.y, h2_, l2_);
            pk_split(kc1.z, kc1.w, h3_, l3_);
            kbhi0 = mk8((int)h0_, (int)h1_, (int)h2_, (int)h3_);
            kblo0 = mk8((int)l0_, (int)l1_, (int)l2_, (int)l3_);
            pk_split(kc2.x, kc2.y, h0_, l0_);
            pk_split(kc2.z, kc2.w, h1_, l1_);
            pk_split(kc3.x, kc3.y, h2_, l2_);
            pk_split(kc3.z, kc3.w, h3_, l3_);
            kbhi1 = mk8((int)h0_, (int)h1_, (int)h2_, (int)h3_);
            kblo1 = mk8((int)l0_, (int)l1_, (int)l2_, (int)l3_);
        }
        // kc is dead now -> reload in place for tile mt+4 (zero extra regs)
        if (mt + 4 < 13) {
            int row = (mt + 4) * 16 + l16; if (row > T - 1) row = T - 1;
            const float* kr = kb_base + (size_t)row * D + quad * 8;
            kc0 = *(const float4*)(kr);
            kc1 = *(const float4*)(kr + 4);
            kc2 = *(const float4*)(kr + 32);
            kc3 = *(const float4*)(kr + 36);
        }
        // ---- Layer 1: 5 h-tiles -> named split-bf16 words ----
        uint2 hw0, hw1, hw2, hw3, hw4, lw0, lw1, lw2, lw3, lw4;
        L1_HT(0, hw0, lw0)
        L1_HT(1, hw1, lw1)
        L1_HT(2, hw2, lw2)
        L1_HT(3, hw3, lw3)
        L1_HT(4, hw4, lw4)
        // ---- Layer 2 A-frags via quad-level bpermute transpose ----
        short8 a2hi0, a2lo0, a2hi1, a2lo1, a2hi2, a2lo2;
        TRN(hw0, hw1, lw0, lw1, a2hi0, a2lo0)
        TRN(hw2, hw3, lw2, lw3, a2hi1, a2lo1)
        TRN2(hw4, lw4, a2hi2, a2lo2)
        // ---- Layer 2 + head ----
        float part0 = 0.0f, part1 = 0.0f, part2 = 0.0f, part3 = 0.0f;
        L2_NT(0)
        L2_NT(1)
        L2_NT(2)
        // reduce over the 16 g-cols (lane bits 0..3)
        #pragma unroll
        for (int off = 1; off < 16; off <<= 1) {
            part0 += __shfl_xor(part0, off);
            part1 += __shfl_xor(part1, off);
            part2 += __shfl_xor(part2, off);
            part3 += __shfl_xor(part3, off);
        }
        if (l16 == 0) {
            float4 p = {part0, part1, part2, part3};
            *(float4*)&s_logits[mt * 16 + quad * 4] = p;
        }
    }
    __syncthreads();

    // ---- Phase 2: mask + softmax over T (pads -> -inf => exp 0) ----
    float logit = -INFINITY;
    if (tid < T)
        logit = (mval == 0) ? NEG_INF_V : s_logits[tid];

    float m = logit;
    #pragma unroll
    for (int off = 32; off > 0; off >>= 1) m = fmaxf(m, __shfl_xor(m, off));
    if (lane == 0) s_red[wv] = m;
    __syncthreads();
    m = fmaxf(fmaxf(s_red[0], s_red[1]), fmaxf(s_red[2], s_red[3]));
    const float e = expf(logit - m);
    s_w[tid] = e;
    float ssum = e;
    #pragma unroll
    for (int off = 32; off > 0; off >>= 1) ssum += __shfl_xor(ssum, off);
    if (lane == 0) s_red[4 + wv] = ssum;
    __syncthreads();
    const float inv = 1.0f / (s_red[4] + s_red[5] + s_red[6] + s_red[7]);

    // ---- out[b,d] = sum_t w_t * v[b,t,d] (coalesced in d) ----
    const int d = tid & (D - 1);
    const int c = tid >> 6;
    constexpr int TC = T / 4;          // 50
    float acc2 = 0.0f;
    const float* vp = v + ((size_t)b * T + c * TC) * D + d;
    #pragma unroll 10
    for (int t = 0; t < TC; ++t)
        acc2 = fmaf(s_w[c * TC + t], vp[t * D], acc2);
    s_part[c][d] = acc2;
    __syncthreads();
    if (tid < D) {
        out[(size_t)b * D + tid] =
            (s_part[0][tid] + s_part[1][tid] + s_part[2][tid] + s_part[3][tid]) * inv;
    }
}

extern "C" void kernel_launch(void* const* d_in, const int* in_sizes, int n_in,
                              void* d_out, int out_size, void* d_ws, size_t ws_size,
                              hipStream_t stream) {
    const float* q  = (const float*)d_in[0];
    const float* k  = (const float*)d_in[1];
    const float* v  = (const float*)d_in[2];
    const float* W0 = (const float*)d_in[3];
    const float* b0 = (const float*)d_in[4];
    const float* a0 = (const float*)d_in[5];
    const float* W1 = (const float*)d_in[6];
    const float* b1 = (const float*)d_in[7];
    const float* a1 = (const float*)d_in[8];
    const float* Wo = (const float*)d_in[9];
    const int*  mask = (const int*)d_in[11];
    float* out = (float*)d_out;

    const int B = in_sizes[0] / D;            // 2048

    short* w1fHi = (short*)d_ws;              // 4608 shorts
    short* w1fLo = w1fHi + 4608;              // 4608 shorts (18432 B total)

    fold_w1<<<dim3(1), dim3(256), 0, stream>>>(W1, w1fHi, w1fLo);
    attn_fused<<<dim3(B), dim3(BLOCK), 0, stream>>>(
        q, k, v, W0, b0, a0, w1fHi, w1fLo, b1, a1, Wo, mask, out);
}